// Round 2
// baseline (346.245 us; speedup 1.0000x reference)
//
#include <hip/hip_runtime.h>
#include <cstdint>
#include <cstddef>

// ---------------- problem constants ----------------
static constexpr int NB  = 8;     // batch
static constexpr int S   = 512;   // seq len
static constexpr int HID = 1024;
static constexpr int NH  = 16;    // heads
static constexpr int DH  = 64;    // head dim
static constexpr int P2  = 1024;  // 2*ATT_SPAN

typedef __bf16 v8bf  __attribute__((ext_vector_type(8)));
typedef float  f32x4 __attribute__((ext_vector_type(4)));

__device__ __forceinline__ float bf2f(short u) {
  union { float f; unsigned int i; } v; v.i = ((unsigned int)(unsigned short)u) << 16; return v.f;
}
__device__ __forceinline__ short f2bf(float f) {
  union { float f; unsigned int i; } v; v.f = f;
  unsigned int r = v.i + 0x7FFFu + ((v.i >> 16) & 1u);  // RNE
  return (short)(r >> 16);
}

// ---------------- projection GEMM (cast fused; V emitted transposed) ----------
// C = A @ W^T + bias.  A:[M,1024] fp32 row-major, W:[1024,1024] fp32 ([n][k]).
// z=0,1 -> q,k as [b][h][s][d] bf16; z=2 -> v as [b][h][d][s] bf16 (transposed);
// z=3 -> pos as [h][p][d] bf16.
__launch_bounds__(256)
__global__ void proj_gemm(const float* __restrict__ X, const float* __restrict__ R,
                          const float* __restrict__ Wq, const float* __restrict__ Wk,
                          const float* __restrict__ Wv, const float* __restrict__ Wpk,
                          const float* __restrict__ bq, const float* __restrict__ bk_,
                          const float* __restrict__ bv_, const float* __restrict__ bpk,
                          short* __restrict__ qo, short* __restrict__ ko,
                          short* __restrict__ vto, short* __restrict__ po) {
  const int z = blockIdx.z;
  const float* A; const float* W; const float* bias; short* out; int M;
  if      (z == 0) { A = X; W = Wq;  bias = bq;  out = qo;  M = 4096; }
  else if (z == 1) { A = X; W = Wk;  bias = bk_; out = ko;  M = 4096; }
  else if (z == 2) { A = X; W = Wv;  bias = bv_; out = vto; M = 4096; }
  else             { A = R; W = Wpk; bias = bpk; out = po;  M = 1024; }
  const int m0 = blockIdx.x * 128;
  if (m0 >= M) return;
  const int n0 = blockIdx.y * 128;
  const int K = 1024;

  __shared__ short Al[128 * 40];  // stride 40 shorts = 80B
  __shared__ short Bl[128 * 40];

  const int t = threadIdx.x;
  const int w = t >> 6, lane = t & 63, q4 = lane >> 4, cc = lane & 15;
  const int wm = w >> 1, wn = w & 1;

  f32x4 acc[4][4] = {};

  for (int k0 = 0; k0 < K; k0 += 32) {
    __syncthreads();
    for (int ch = t; ch < 512; ch += 256) {
      int row = ch >> 2, kc = (ch & 3) << 3;
      const float* pa = &A[(size_t)(m0 + row) * K + k0 + kc];
      float4 x0 = *(const float4*)pa, x1 = *(const float4*)(pa + 4);
      union { short s[8]; int4 v; } ua;
      ua.s[0] = f2bf(x0.x); ua.s[1] = f2bf(x0.y); ua.s[2] = f2bf(x0.z); ua.s[3] = f2bf(x0.w);
      ua.s[4] = f2bf(x1.x); ua.s[5] = f2bf(x1.y); ua.s[6] = f2bf(x1.z); ua.s[7] = f2bf(x1.w);
      *(int4*)(&Al[row * 40 + kc]) = ua.v;
      const float* pb = &W[(size_t)(n0 + row) * K + k0 + kc];
      float4 y0 = *(const float4*)pb, y1 = *(const float4*)(pb + 4);
      union { short s[8]; int4 v; } ub;
      ub.s[0] = f2bf(y0.x); ub.s[1] = f2bf(y0.y); ub.s[2] = f2bf(y0.z); ub.s[3] = f2bf(y0.w);
      ub.s[4] = f2bf(y1.x); ub.s[5] = f2bf(y1.y); ub.s[6] = f2bf(y1.z); ub.s[7] = f2bf(y1.w);
      *(int4*)(&Bl[row * 40 + kc]) = ub.v;
    }
    __syncthreads();
    v8bf af[4], bfg[4];
    for (int mt = 0; mt < 4; mt++)
      af[mt] = *(const v8bf*)(&Al[(wm * 64 + mt * 16 + cc) * 40 + q4 * 8]);
    for (int nt = 0; nt < 4; nt++)
      bfg[nt] = *(const v8bf*)(&Bl[(wn * 64 + nt * 16 + cc) * 40 + q4 * 8]);
    for (int mt = 0; mt < 4; mt++)
      for (int nt = 0; nt < 4; nt++)
        acc[mt][nt] = __builtin_amdgcn_mfma_f32_16x16x32_bf16(af[mt], bfg[nt], acc[mt][nt], 0, 0, 0);
  }

  for (int mt = 0; mt < 4; mt++) {
    for (int nt = 0; nt < 4; nt++) {
      int n = n0 + wn * 64 + nt * 16 + cc;
      float bsv = bias[n];
      if (z == 2) {
        // packed store of 4 consecutive s values to V^T [b][h][d][s]
        int m_base = m0 + wm * 64 + mt * 16 + q4 * 4;
        int bb = m_base >> 9, ss = m_base & 511, hh = n >> 6, dd = n & 63;
        short4 st;
        st.x = f2bf(acc[mt][nt][0] + bsv);
        st.y = f2bf(acc[mt][nt][1] + bsv);
        st.z = f2bf(acc[mt][nt][2] + bsv);
        st.w = f2bf(acc[mt][nt][3] + bsv);
        *(short4*)(&out[(((size_t)bb * 16 + hh) * 64 + dd) * 512 + ss]) = st;
      } else {
        for (int r = 0; r < 4; r++) {
          int m = m0 + wm * 64 + mt * 16 + q4 * 4 + r;
          float val = acc[mt][nt][r] + bsv;
          size_t idx;
          if (z < 2)
            idx = ((size_t)(m >> 9) * 16 + (n >> 6)) * (512 * 64) + (size_t)(m & 511) * 64 + (n & 63);
          else
            idx = (size_t)(n >> 6) * (1024 * 64) + (size_t)m * 64 + (n & 63);
          out[idx] = f2bf(val);
        }
      }
    }
  }
}

// ---------------- fused disentangled attention ----------------
// grid: (S/64, NH, NB); block 256 = 4 waves; wave w owns i-rows [i0+16w, i0+16w+16)
// LDS 36864 B -> 4 blocks/CU; Q/K/V fragments come straight from global (L1).
__launch_bounds__(256, 4)
__global__ void attn(const short* __restrict__ qb, const short* __restrict__ kb,
                     const short* __restrict__ vtb, const short* __restrict__ posb,
                     const float* __restrict__ mask, float* __restrict__ out) {
  const int i0 = blockIdx.x * 64;
  const int h  = blockIdx.y;
  const int b  = blockIdx.z;

  __shared__ short Pl[128 * 72];   // posSlice [p'][d]
  __shared__ short SgPr[64 * 72];  // c2p band (pre-gathered) -> then probs bf16 [a][jj]
  __shared__ short Sh[64 * 72];    // p2c band (pre-gathered) [a][jj]

  const int t = threadIdx.x, w = t >> 6, lane = t & 63, q4 = lane >> 4, cc = lane & 15;
  const size_t bh = ((size_t)b * NH + h) * (S * DH);
  const short* qp  = qb  + bh;
  const short* kp  = kb  + bh;
  const short* vtp = vtb + bh;      // [d][s]
  const short* pp  = posb + (size_t)h * (P2 * DH);

  // Q fragments direct from global (one-time)
  v8bf aq0 = *(const v8bf*)(&qp[(size_t)(i0 + w * 16 + cc) * DH + q4 * 8]);
  v8bf aq1 = *(const v8bf*)(&qp[(size_t)(i0 + w * 16 + cc) * DH + 32 + q4 * 8]);

  f32x4 Oc[4] = {};
  float mrow[4], lrow[4];
  for (int r = 0; r < 4; r++) { mrow[r] = -__builtin_inff(); lrow[r] = 0.f; }

  const float inv_s1 = 0.14433756729740643f;   // 1/sqrt(3*H)
  const float inv_s2 = 0.018042195912175804f;  // 1/sqrt(3*HID)

  for (int jt = 0; jt < 8; jt++) {
    const int j0 = jt * 64;
    const int r0 = i0 - j0 + 512;
    __syncthreads();  // A: prior iter's Pl/Sh reads complete

    // stage posSlice rows p'=0..127 -> pos[r0-63+p'] (row 127 never read in-band)
    for (int ch = t; ch < 1024; ch += 256) {
      int pr = ch >> 3, dc = (ch & 7) << 3;
      int p = r0 - 63 + pr;
      p = min(max(p, 0), 1023);
      *(int4*)(&Pl[pr * 72 + dc]) = *(const int4*)(&pp[(size_t)p * DH + dc]);
    }
    __syncthreads();  // B

    // content scores: Q strip [16,64] @ K^T (K frags direct from global)
    f32x4 accc[4];
    #pragma unroll
    for (int nt = 0; nt < 4; nt++) {
      v8bf k0f = *(const v8bf*)(&kp[(size_t)(j0 + nt * 16 + cc) * DH + q4 * 8]);
      v8bf k1f = *(const v8bf*)(&kp[(size_t)(j0 + nt * 16 + cc) * DH + 32 + q4 * 8]);
      f32x4 a = {};
      a = __builtin_amdgcn_mfma_f32_16x16x32_bf16(aq0, k0f, a, 0, 0, 0);
      a = __builtin_amdgcn_mfma_f32_16x16x32_bf16(aq1, k1f, a, 0, 0, 0);
      accc[nt] = a;
    }

    // G = Q strip @ posSlice^T, trimmed to the 5 fragments covering the band;
    // scatter in-band elements straight into score-shaped SgPr[a][jj]
    #pragma unroll
    for (int u = 0; u < 5; u++) {
      int ntg = w + u;
      v8bf p0 = *(const v8bf*)(&Pl[(ntg * 16 + cc) * 72 + q4 * 8]);
      v8bf p1 = *(const v8bf*)(&Pl[(ntg * 16 + cc) * 72 + 32 + q4 * 8]);
      f32x4 g = {};
      g = __builtin_amdgcn_mfma_f32_16x16x32_bf16(aq0, p0, g, 0, 0, 0);
      g = __builtin_amdgcn_mfma_f32_16x16x32_bf16(aq1, p1, g, 0, 0, 0);
      #pragma unroll
      for (int r = 0; r < 4; r++) {
        int a_ = w * 16 + q4 * 4 + r;
        int pi = ntg * 16 + cc;
        int jj = a_ - pi + 63;
        if ((unsigned)jj < 64u) SgPr[a_ * 72 + jj] = f2bf(g[r]);
      }
    }

    // H = posSlice @ K^T; scatter in-band elements into Sh[a][jj] (unique writer/slot)
    #pragma unroll
    for (int m2 = 0; m2 < 2; m2++) {
      v8bf a0 = *(const v8bf*)(&Pl[(w * 32 + m2 * 16 + cc) * 72 + q4 * 8]);
      v8bf a1 = *(const v8bf*)(&Pl[(w * 32 + m2 * 16 + cc) * 72 + 32 + q4 * 8]);
      #pragma unroll
      for (int nt = 0; nt < 4; nt++) {
        v8bf k0f = *(const v8bf*)(&kp[(size_t)(j0 + nt * 16 + cc) * DH + q4 * 8]);
        v8bf k1f = *(const v8bf*)(&kp[(size_t)(j0 + nt * 16 + cc) * DH + 32 + q4 * 8]);
        f32x4 hh = {};
        hh = __builtin_amdgcn_mfma_f32_16x16x32_bf16(a0, k0f, hh, 0, 0, 0);
        hh = __builtin_amdgcn_mfma_f32_16x16x32_bf16(a1, k1f, hh, 0, 0, 0);
        #pragma unroll
        for (int r = 0; r < 4; r++) {
          int pi = w * 32 + m2 * 16 + q4 * 4 + r;
          int jj = nt * 16 + cc;
          int a_ = pi + jj - 63;
          if ((unsigned)a_ < 64u) Sh[a_ * 72 + jj] = f2bf(hh[r]);
        }
      }
    }
    __syncthreads();  // C: Sh is cross-wave

    // assemble scores + online softmax
    float sc[4][4];
    float tmax[4] = { -__builtin_inff(), -__builtin_inff(), -__builtin_inff(), -__builtin_inff() };
    #pragma unroll
    for (int nt = 0; nt < 4; nt++) {
      int jj = nt * 16 + cc;
      float mk = mask[(size_t)b * S + j0 + jj];
      #pragma unroll
      for (int r = 0; r < 4; r++) {
        int a_ = w * 16 + q4 * 4 + r;
        float s = accc[nt][r] * inv_s1
                + bf2f(SgPr[a_ * 72 + jj]) * inv_s2
                + bf2f(Sh[a_ * 72 + jj]) * inv_s1
                + mk;
        sc[nt][r] = s;
        tmax[r] = fmaxf(tmax[r], s);
      }
    }
    #pragma unroll
    for (int off = 1; off < 16; off <<= 1)
      #pragma unroll
      for (int r = 0; r < 4; r++) tmax[r] = fmaxf(tmax[r], __shfl_xor(tmax[r], off, 64));

    float alpha[4], psum[4];
    #pragma unroll
    for (int r = 0; r < 4; r++) {
      float mnew = fmaxf(mrow[r], tmax[r]);
      alpha[r] = __expf(mrow[r] - mnew);
      mrow[r] = mnew;
      psum[r] = 0.f;
    }
    // overwrite SgPr with probs (all reads above already in registers; same-wave rows)
    #pragma unroll
    for (int nt = 0; nt < 4; nt++)
      #pragma unroll
      for (int r = 0; r < 4; r++) {
        float p = __expf(sc[nt][r] - mrow[r]);
        psum[r] += p;
        SgPr[(w * 16 + q4 * 4 + r) * 72 + nt * 16 + cc] = f2bf(p);
      }
    #pragma unroll
    for (int off = 1; off < 16; off <<= 1)
      #pragma unroll
      for (int r = 0; r < 4; r++) psum[r] += __shfl_xor(psum[r], off, 64);
    #pragma unroll
    for (int r = 0; r < 4; r++) lrow[r] = lrow[r] * alpha[r] + psum[r];
    #pragma unroll
    for (int dt = 0; dt < 4; dt++)
      #pragma unroll
      for (int r = 0; r < 4; r++) Oc[dt][r] *= alpha[r];

    // PV: P strip [16,64] @ V; V^T fragments direct from global [d][s]
    #pragma unroll
    for (int kk = 0; kk < 2; kk++) {
      v8bf ap = *(const v8bf*)(&SgPr[(w * 16 + cc) * 72 + kk * 32 + q4 * 8]);
      #pragma unroll
      for (int dt = 0; dt < 4; dt++) {
        v8bf bvf = *(const v8bf*)(&vtp[(size_t)(dt * 16 + cc) * S + j0 + kk * 32 + q4 * 8]);
        Oc[dt] = __builtin_amdgcn_mfma_f32_16x16x32_bf16(ap, bvf, Oc[dt], 0, 0, 0);
      }
    }
  }

  // epilogue: out[b][i][h*64+d] fp32
  #pragma unroll
  for (int dt = 0; dt < 4; dt++) {
    #pragma unroll
    for (int r = 0; r < 4; r++) {
      int i = i0 + w * 16 + q4 * 4 + r;
      int d = dt * 16 + cc;
      out[((size_t)b * S + i) * HID + h * 64 + d] = Oc[dt][r] / lrow[r];
    }
  }
}

// ---------------- launch ----------------
extern "C" void kernel_launch(void* const* d_in, const int* in_sizes, int n_in,
                              void* d_out, int out_size, void* d_ws, size_t ws_size,
                              hipStream_t stream) {
  const float* hs   = (const float*)d_in[0];
  const float* mask = (const float*)d_in[1];
  // d_in[2] relative_pos == i-j analytically (never clamps for S=512, span 512)
  const float* Wq  = (const float*)d_in[3];
  const float* bq  = (const float*)d_in[4];
  const float* Wk  = (const float*)d_in[5];
  const float* bk  = (const float*)d_in[6];
  const float* Wv  = (const float*)d_in[7];
  const float* bv  = (const float*)d_in[8];
  const float* Wpk = (const float*)d_in[9];
  const float* bpk = (const float*)d_in[10];
  const float* rel = (const float*)d_in[11];
  float* out = (float*)d_out;

  char* ws = (char*)d_ws;
  short* qb   = (short*)(ws);                    // [b][h][s][d] 8 MB
  short* kb   = (short*)(ws + 8388608);          // [b][h][s][d] 8 MB
  short* vtb  = (short*)(ws + 16777216);         // [b][h][d][s] 8 MB
  short* posb = (short*)(ws + 25165824);         // [h][p][d]    2 MB

  proj_gemm<<<dim3(32, 8, 4), 256, 0, stream>>>(hs, rel, Wq, Wk, Wv, Wpk,
                                                bq, bk, bv, bpk, qb, kb, vtb, posb);

  attn<<<dim3(8, 16, 8), 256, 0, stream>>>(qb, kb, vtb, posb, mask, out);
}